// Round 7
// baseline (16.053 us; speedup 1.0000x reference)
//
#include <hip/hip_runtime.h>

// Analytic collapse of the quantum circuit:
//   z = [cos(a)cos(b)*(S00 - S11) - 2*sin(a)*S01] / (S00 + S11)
// with a = ry0[0]+ry1[0], b = rx0[0],
//   S00 = sum(x[0:512]^2), S11 = sum(x[512:1024]^2), S01 = sum(x[0:512]*x[512:1024])
// Output: z replicated 16x per sample.
//
// R7 = R2 (best, 13.7us) with ONE change: regular cached loads instead of
// __builtin_nontemporal_load. Clean NT-vs-cached ablation at the best
// config (2 samples/wave, 8 loads in flight, 8192 waves = 32 waves/CU).

#define DIM 1024
#define HID 16

typedef float fvec4 __attribute__((ext_vector_type(4)));

__global__ __launch_bounds__(256) void qz_kernel(
    const float* __restrict__ x,
    const float* __restrict__ rx0,
    const float* __restrict__ ry0,
    const float* __restrict__ ry1,
    float* __restrict__ out,
    int nSamples)
{
    const int gtid = blockIdx.x * blockDim.x + threadIdx.x;
    const int wave = gtid >> 6;          // one wave64 per 2 samples
    const int lane = threadIdx.x & 63;
    const int s0 = wave * 2;
    if (s0 >= nSamples) return;

    // wave-uniform coefficients
    const float a  = ry0[0] + ry1[0];
    const float b  = rx0[0];
    const float c00  = __cosf(a) * __cosf(b);   // b00 (= -b11)
    const float tb01 = -2.0f * __sinf(a);       // 2*Re(b01)

    const fvec4* r0 = (const fvec4*)(x + (size_t)s0 * DIM);        // sample 0: 256 fvec4
    const fvec4* r1 = (const fvec4*)(x + (size_t)(s0 + 1) * DIM);  // sample 1

    // issue all 8 loads up front (cached this round — ablation vs R2's NT)
    fvec4 p0 = r0[       lane];   // s0 first half
    fvec4 p1 = r0[ 64 + lane];
    fvec4 q0 = r0[128 + lane];    // s0 second half
    fvec4 q1 = r0[192 + lane];
    fvec4 u0 = r1[       lane];   // s1 first half
    fvec4 u1 = r1[ 64 + lane];
    fvec4 v0 = r1[128 + lane];    // s1 second half
    fvec4 v1 = r1[192 + lane];

    float s00, s11, s01;

    s00 = p0.x*p0.x + p0.y*p0.y + p0.z*p0.z + p0.w*p0.w
        + p1.x*p1.x + p1.y*p1.y + p1.z*p1.z + p1.w*p1.w;
    s11 = q0.x*q0.x + q0.y*q0.y + q0.z*q0.z + q0.w*q0.w
        + q1.x*q1.x + q1.y*q1.y + q1.z*q1.z + q1.w*q1.w;
    s01 = p0.x*q0.x + p0.y*q0.y + p0.z*q0.z + p0.w*q0.w
        + p1.x*q1.x + p1.y*q1.y + p1.z*q1.z + p1.w*q1.w;
    float num0 = c00 * (s00 - s11) + tb01 * s01;
    float den0 = s00 + s11;

    s00 = u0.x*u0.x + u0.y*u0.y + u0.z*u0.z + u0.w*u0.w
        + u1.x*u1.x + u1.y*u1.y + u1.z*u1.z + u1.w*u1.w;
    s11 = v0.x*v0.x + v0.y*v0.y + v0.z*v0.z + v0.w*v0.w
        + v1.x*v1.x + v1.y*v1.y + v1.z*v1.z + v1.w*v1.w;
    s01 = u0.x*v0.x + u0.y*v0.y + u0.z*v0.z + u0.w*v0.w
        + u1.x*v1.x + u1.y*v1.y + u1.z*v1.z + u1.w*v1.w;
    float num1 = c00 * (s00 - s11) + tb01 * s01;
    float den1 = s00 + s11;

    // butterfly reduce: 4 independent accumulators through 6 steps
    #pragma unroll
    for (int off = 32; off > 0; off >>= 1) {
        num0 += __shfl_xor(num0, off, 64);
        den0 += __shfl_xor(den0, off, 64);
        num1 += __shfl_xor(num1, off, 64);
        den1 += __shfl_xor(den1, off, 64);
    }

    const float z0 = num0 / den0;
    const float z1 = num1 / den1;

    // 128 B contiguous store per wave: lanes 0..7 each write one fvec4
    if (lane < 8) {
        fvec4* o = (fvec4*)(out + (size_t)s0 * HID);
        const float z = (lane < 4) ? z0 : z1;
        fvec4 zv = {z, z, z, z};
        __builtin_nontemporal_store(zv, &o[lane]);
    }
}

extern "C" void kernel_launch(void* const* d_in, const int* in_sizes, int n_in,
                              void* d_out, int out_size, void* d_ws, size_t ws_size,
                              hipStream_t stream) {
    const float* x   = (const float*)d_in[0];
    const float* rx0 = (const float*)d_in[1];
    const float* ry0 = (const float*)d_in[2];
    const float* ry1 = (const float*)d_in[3];
    float* out = (float*)d_out;

    const int nSamples = in_sizes[0] / DIM;                 // 16384
    const int samplesPerBlock = 8;                          // 4 waves * 2 samples
    const int blocks = (nSamples + samplesPerBlock - 1) / samplesPerBlock;

    qz_kernel<<<blocks, 256, 0, stream>>>(x, rx0, ry0, ry1, out, nSamples);
}

// Round 8
// 13.669 us; speedup vs baseline: 1.1744x; 1.1744x over previous
//
#include <hip/hip_runtime.h>

// Analytic collapse of the quantum circuit:
//   z = [cos(a)cos(b)*(S00 - S11) - 2*sin(a)*S01] / (S00 + S11)
// with a = ry0[0]+ry1[0], b = rx0[0],
//   S00 = sum(x[0:512]^2), S11 = sum(x[512:1024]^2), S01 = sum(x[0:512]*x[512:1024])
// Output: z replicated 16x per sample.
//
// R8 = R2 verbatim (session best, 13.7us). Config is the proven optimum:
// - 2 samples/wave: whole problem = ONE full-occupancy generation
//   (2048 blocks = 8 blocks/CU x 4 waves = 32 waves/CU on 256 CUs).
// - NT loads: +17% vs cached (R7 ablation) — no cache allocation for a
//   stream that is evicted between replays by the harness's 268MB fills.
// - 8 float4 loads in flight/wave; coefficients folded per-lane so the
//   butterfly reduces 4 accumulators through 6 steps; coalesced 128B store.

#define DIM 1024
#define HID 16

typedef float fvec4 __attribute__((ext_vector_type(4)));

__global__ __launch_bounds__(256) void qz_kernel(
    const float* __restrict__ x,
    const float* __restrict__ rx0,
    const float* __restrict__ ry0,
    const float* __restrict__ ry1,
    float* __restrict__ out,
    int nSamples)
{
    const int gtid = blockIdx.x * blockDim.x + threadIdx.x;
    const int wave = gtid >> 6;          // one wave64 per 2 samples
    const int lane = threadIdx.x & 63;
    const int s0 = wave * 2;
    if (s0 >= nSamples) return;

    // wave-uniform coefficients
    const float a  = ry0[0] + ry1[0];
    const float b  = rx0[0];
    const float c00  = __cosf(a) * __cosf(b);   // b00 (= -b11)
    const float tb01 = -2.0f * __sinf(a);       // 2*Re(b01)

    const fvec4* r0 = (const fvec4*)(x + (size_t)s0 * DIM);        // sample 0: 256 fvec4
    const fvec4* r1 = (const fvec4*)(x + (size_t)(s0 + 1) * DIM);  // sample 1

    // issue all 8 loads up front (64 B/lane per sample half-pair)
    fvec4 p0 = __builtin_nontemporal_load(&r0[       lane]);  // s0 first half
    fvec4 p1 = __builtin_nontemporal_load(&r0[ 64 + lane]);
    fvec4 q0 = __builtin_nontemporal_load(&r0[128 + lane]);   // s0 second half
    fvec4 q1 = __builtin_nontemporal_load(&r0[192 + lane]);
    fvec4 u0 = __builtin_nontemporal_load(&r1[       lane]);  // s1 first half
    fvec4 u1 = __builtin_nontemporal_load(&r1[ 64 + lane]);
    fvec4 v0 = __builtin_nontemporal_load(&r1[128 + lane]);   // s1 second half
    fvec4 v1 = __builtin_nontemporal_load(&r1[192 + lane]);

    float s00, s11, s01;

    s00 = p0.x*p0.x + p0.y*p0.y + p0.z*p0.z + p0.w*p0.w
        + p1.x*p1.x + p1.y*p1.y + p1.z*p1.z + p1.w*p1.w;
    s11 = q0.x*q0.x + q0.y*q0.y + q0.z*q0.z + q0.w*q0.w
        + q1.x*q1.x + q1.y*q1.y + q1.z*q1.z + q1.w*q1.w;
    s01 = p0.x*q0.x + p0.y*q0.y + p0.z*q0.z + p0.w*q0.w
        + p1.x*q1.x + p1.y*q1.y + p1.z*q1.z + p1.w*q1.w;
    float num0 = c00 * (s00 - s11) + tb01 * s01;
    float den0 = s00 + s11;

    s00 = u0.x*u0.x + u0.y*u0.y + u0.z*u0.z + u0.w*u0.w
        + u1.x*u1.x + u1.y*u1.y + u1.z*u1.z + u1.w*u1.w;
    s11 = v0.x*v0.x + v0.y*v0.y + v0.z*v0.z + v0.w*v0.w
        + v1.x*v1.x + v1.y*v1.y + v1.z*v1.z + v1.w*v1.w;
    s01 = u0.x*v0.x + u0.y*v0.y + u0.z*v0.z + u0.w*v0.w
        + u1.x*v1.x + u1.y*v1.y + u1.z*v1.z + u1.w*v1.w;
    float num1 = c00 * (s00 - s11) + tb01 * s01;
    float den1 = s00 + s11;

    // butterfly reduce: 4 independent accumulators through 6 steps
    #pragma unroll
    for (int off = 32; off > 0; off >>= 1) {
        num0 += __shfl_xor(num0, off, 64);
        den0 += __shfl_xor(den0, off, 64);
        num1 += __shfl_xor(num1, off, 64);
        den1 += __shfl_xor(den1, off, 64);
    }

    const float z0 = num0 / den0;
    const float z1 = num1 / den1;

    // 128 B contiguous store per wave: lanes 0..7 each write one fvec4
    if (lane < 8) {
        fvec4* o = (fvec4*)(out + (size_t)s0 * HID);
        const float z = (lane < 4) ? z0 : z1;
        fvec4 zv = {z, z, z, z};
        __builtin_nontemporal_store(zv, &o[lane]);
    }
}

extern "C" void kernel_launch(void* const* d_in, const int* in_sizes, int n_in,
                              void* d_out, int out_size, void* d_ws, size_t ws_size,
                              hipStream_t stream) {
    const float* x   = (const float*)d_in[0];
    const float* rx0 = (const float*)d_in[1];
    const float* ry0 = (const float*)d_in[2];
    const float* ry1 = (const float*)d_in[3];
    float* out = (float*)d_out;

    const int nSamples = in_sizes[0] / DIM;                 // 16384
    const int samplesPerBlock = 8;                          // 4 waves * 2 samples
    const int blocks = (nSamples + samplesPerBlock - 1) / samplesPerBlock;

    qz_kernel<<<blocks, 256, 0, stream>>>(x, rx0, ry0, ry1, out, nSamples);
}